// Round 2
// baseline (159.575 us; speedup 1.0000x reference)
//
#include <hip/hip_runtime.h>

namespace {

constexpr int Hh = 512;    // input H
constexpr int Ww = 512;    // input W
constexpr int OH = 1024;   // output H
constexpr int OW = 1024;   // output W
constexpr int SEG  = 128;  // 4-col segments per row (512/4)
constexpr int NB_Y = 256;  // y-blocks (2 input rows each)
constexpr int NBC  = 48;   // 16 batches * 3 out channels
constexpr int NWG  = NB_Y * NBC;  // 12288, divisible by 8

// Each thread: one input row y, 4 input cols x0..x0+3 -> 8x2 output strip,
// summed over 4 bands. Separable: row-combine (3 up-rows x 6 cols),
// col-combine (3 up-rows x 9 up-cols), then 2x2 filter accumulate.
__global__ __launch_bounds__(256) void ihaar(
    const float* __restrict__ x,
    const float* __restrict__ f0,
    const float* __restrict__ f1,
    const float* __restrict__ f2,
    const float* __restrict__ f3,
    float* __restrict__ out)
{
  // XCD-chunked bijective swizzle (NWG % 8 == 0): each XCD gets a
  // contiguous logical chunk -> vertical row reuse hits its own L2.
  const int bid = blockIdx.x;
  const int wg  = (bid & 7) * (NWG / 8) + (bid >> 3);
  const int bc   = wg / NB_Y;          // 0..47, b*3+c
  const int yblk = wg - bc * NB_Y;     // 0..255
  const int b = bc / 3;
  const int c = bc - 3 * b;

  const int tx = threadIdx.x & (SEG - 1);   // col segment 0..127
  const int ty = threadIdx.x >> 7;          // 0..1
  const int y  = 2 * yblk + ty;             // input row 0..511
  const int x0 = tx * 4;                    // input col base

  const float4 F[4] = { *(const float4*)f0, *(const float4*)f1,
                        *(const float4*)f2, *(const float4*)f3 };

  // Row (vertical) upsample weights for up-rows A=2y-1, B=2y, C=2y+1
  float wA0, wA1, wB0, wB1, wC1, wC2;
  if (y > 0) { wA0 = 0.75f; wA1 = 0.25f; wB0 = 0.25f; wB1 = 0.75f; }
  else       { wA0 = 0.0f;  wA1 = 0.0f;  wB0 = 0.0f;  wB1 = 1.0f; }
  if (y < Hh - 1) { wC1 = 0.75f; wC2 = 0.25f; } else { wC1 = 1.0f; wC2 = 0.0f; }

  // Column edge weights. U index m corresponds to up-col (2*x0 - 1 + m).
  const bool le = (x0 == 0), re = (x0 + 4 == Ww);
  const float cmL = le ? 0.f : 0.75f, cma = le ? 0.f : 0.25f;  // U[0] (up col 2x0-1; pad-zero at left edge)
  const float c0L = le ? 0.f : 0.25f, c0a = le ? 1.f : 0.75f;  // U[1] (up col 2x0)
  const float c7a = re ? 1.f : 0.75f, c7R = re ? 0.f : 0.25f;  // U[8] (up col 2x0+7)

  const int u0 = (y > 0) ? y - 1 : 0;
  const int u2 = (y < Hh - 1) ? y + 1 : y;
  const int lI = le ? 0 : x0 - 1;
  const int rI = re ? Ww - 1 : x0 + 4;

  float o0[8], o1[8];
#pragma unroll
  for (int j = 0; j < 8; ++j) { o0[j] = 0.f; o1[j] = 0.f; }

#pragma unroll
  for (int g = 0; g < 4; ++g) {
    const float* Xp = x + (size_t)(b * 12 + g * 3 + c) * (Hh * Ww);
    const float* p0 = Xp + (size_t)u0 * Ww;
    const float* p1 = Xp + (size_t)y  * Ww;
    const float* p2 = Xp + (size_t)u2 * Ww;

    const float4 q0 = *(const float4*)(p0 + x0);
    const float4 q1 = *(const float4*)(p1 + x0);
    const float4 q2 = *(const float4*)(p2 + x0);
    const float q0L = p0[lI], q0R = p0[rI];
    const float q1L = p1[lI], q1R = p1[rI];
    const float q2L = p2[lI], q2R = p2[rI];

    // Row-combine: up-rows A/B/C at 6 input cols {L, a0..a3, R}
    float RA[6], RB[6], RC[6];
    {
      const float i0[6] = { q0L, q0.x, q0.y, q0.z, q0.w, q0R };
      const float i1[6] = { q1L, q1.x, q1.y, q1.z, q1.w, q1R };
      const float i2[6] = { q2L, q2.x, q2.y, q2.z, q2.w, q2R };
#pragma unroll
      for (int i = 0; i < 6; ++i) {
        RA[i] = wA0 * i0[i] + wA1 * i1[i];
        RB[i] = wB0 * i0[i] + wB1 * i1[i];
        RC[i] = wC1 * i1[i] + wC2 * i2[i];
      }
    }

    // Col-combine: 9 up-cols (static indices only; no runtime ptr select)
    float UA[9], UB[9], UC[9];
#define COLC(U, R)                              \
    U[0] = cmL * R[0] + cma * R[1];             \
    U[1] = c0L * R[0] + c0a * R[1];             \
    U[2] = 0.75f * R[1] + 0.25f * R[2];         \
    U[3] = 0.25f * R[1] + 0.75f * R[2];         \
    U[4] = 0.75f * R[2] + 0.25f * R[3];         \
    U[5] = 0.25f * R[2] + 0.75f * R[3];         \
    U[6] = 0.75f * R[3] + 0.25f * R[4];         \
    U[7] = 0.25f * R[3] + 0.75f * R[4];         \
    U[8] = c7a * R[4] + c7R * R[5];
    COLC(UA, RA)
    COLC(UB, RB)
    COLC(UC, RC)
#undef COLC

    // 2x2 filter accumulate: out col j uses up-cols U[j], U[j+1]
    const float f00 = F[g].x, f01 = F[g].y, f10 = F[g].z, f11 = F[g].w;
#pragma unroll
    for (int j = 0; j < 8; ++j) {
      o0[j] += f00 * UA[j] + f01 * UA[j + 1] + f10 * UB[j] + f11 * UB[j + 1];
      o1[j] += f00 * UB[j] + f01 * UB[j + 1] + f10 * UC[j] + f11 * UC[j + 1];
    }
  }

  float* op = out + ((size_t)bc * OH + 2 * y) * OW + 2 * x0;
  *(float4*)(op)          = make_float4(o0[0], o0[1], o0[2], o0[3]);
  *(float4*)(op + 4)      = make_float4(o0[4], o0[5], o0[6], o0[7]);
  *(float4*)(op + OW)     = make_float4(o1[0], o1[1], o1[2], o1[3]);
  *(float4*)(op + OW + 4) = make_float4(o1[4], o1[5], o1[6], o1[7]);
}

} // namespace

extern "C" void kernel_launch(void* const* d_in, const int* in_sizes, int n_in,
                              void* d_out, int out_size, void* d_ws, size_t ws_size,
                              hipStream_t stream) {
  const float* x   = (const float*)d_in[0];
  const float* fll = (const float*)d_in[1];
  const float* flh = (const float*)d_in[2];
  const float* fhl = (const float*)d_in[3];
  const float* fhh = (const float*)d_in[4];
  float* out = (float*)d_out;

  ihaar<<<dim3(NWG), 256, 0, stream>>>(x, fll, flh, fhl, fhh, out);
}

// Round 4
// 77.241 us; speedup vs baseline: 2.0660x; 2.0660x over previous
//
#include <hip/hip_runtime.h>

namespace {

constexpr int Hh = 512, Ww = 512, OH = 1024, OW = 1024;
constexpr int NB_Y = 256;             // y-blocks (2 input rows each)
constexpr int NBC  = 48;              // 16 batches * 3 out channels
constexpr int NWG  = NB_Y * NBC;      // 12288, % 8 == 0

typedef float f32x4 __attribute__((ext_vector_type(4)));

// Thread: 1 input row, 4 input cols (float4) -> 8x2 output strip, 4 bands.
// Wave: 64 lanes = contiguous 256-col half-row; neighbor V values via shfl.
// Block: 4 waves = 2 input rows x 2 half-rows.
__global__ __launch_bounds__(256) void ihaar(
    const float* __restrict__ x,
    const float* __restrict__ f0,
    const float* __restrict__ f1,
    const float* __restrict__ f2,
    const float* __restrict__ f3,
    float* __restrict__ out)
{
  // XCD-chunked bijective swizzle (NWG % 8 == 0)
  const int bid = blockIdx.x;
  const int wg  = (bid & 7) * (NWG / 8) + (bid >> 3);
  const int bc   = wg / NB_Y;          // b*3 + c
  const int yblk = wg - bc * NB_Y;
  const int b = bc / 3;
  const int c = bc - 3 * b;

  const int t    = threadIdx.x;
  const int lane = t & 63;
  const int wv   = t >> 6;
  const int half = wv & 1;
  const int ty   = wv >> 1;
  const int y    = 2 * yblk + ty;      // input row
  const int x0   = half * 256 + lane * 4;

  const float4 F[4] = { *(const float4*)f0, *(const float4*)f1,
                        *(const float4*)f2, *(const float4*)f3 };

  const int u0r = (y > 0) ? y - 1 : 0;
  const int u2r = (y < Hh - 1) ? y + 1 : y;

  // seam lanes: half-row boundary (col 255|256), not image edge
  const bool needL = (lane == 0)  && (half == 1);   // needs col 255
  const bool needR = (lane == 63) && (half == 0);   // needs col 256
  const bool le = (x0 == 0), re = (x0 == Ww - 4);

  float e0=0.f,e1=0.f,e2=0.f,e3=0.f,e4=0.f,e5=0.f,e6=0.f,e7=0.f;
  float o0=0.f,o1=0.f,o2=0.f,o3=0.f,o4=0.f,o5=0.f,o6=0.f,o7=0.f;

#pragma unroll
  for (int g = 0; g < 4; ++g) {
    const float* Xp = x + (size_t)(b * 12 + g * 3 + c) * (Hh * Ww);
    const float4 q0 = *(const float4*)(Xp + (size_t)u0r * Ww + x0);
    const float4 q1 = *(const float4*)(Xp + (size_t)y   * Ww + x0);
    const float4 q2 = *(const float4*)(Xp + (size_t)u2r * Ww + x0);
    float s0 = 0.f, s1 = 0.f, s2 = 0.f;
    if (needL || needR) {
      const int sc = needL ? (x0 - 1) : (x0 + 4);   // 255 or 256
      s0 = Xp[(size_t)u0r * Ww + sc];
      s1 = Xp[(size_t)y   * Ww + sc];
      s2 = Xp[(size_t)u2r * Ww + sc];
    }

    // rank-1 split: f = u (x) v, u = (f00, f10), v = (1, f01/f00)
    const float f00 = F[g].x, f01 = F[g].y, f10 = F[g].z;
    const float uu0 = f00, uu1 = f10;
    const float vv1 = f01 * __builtin_amdgcn_rcpf(f00);

    // vertical taps: parity 0 over (X[y-1],X[y]); parity 1 over 3 rows
    float pa0, pa1, pb0, pb1, pb2;
    if (y > 0) { pa0 = 0.75f*uu0 + 0.25f*uu1; pa1 = 0.25f*uu0 + 0.75f*uu1; }
    else       { pa0 = 0.f;                   pa1 = uu1; }
    if (y == 0)           { pb0 = 0.f;         pb1 = uu0 + 0.75f*uu1;   pb2 = 0.25f*uu1; }
    else if (y == Hh - 1) { pb0 = 0.25f*uu0;   pb1 = 0.75f*uu0 + uu1;   pb2 = 0.f; }
    else                  { pb0 = 0.25f*uu0;   pb1 = 0.75f*(uu0+uu1);   pb2 = 0.25f*uu1; }

    const float Ve0 = pa0*q0.x + pa1*q1.x;
    const float Ve1 = pa0*q0.y + pa1*q1.y;
    const float Ve2 = pa0*q0.z + pa1*q1.z;
    const float Ve3 = pa0*q0.w + pa1*q1.w;
    const float Vo0 = pb0*q0.x + pb1*q1.x + pb2*q2.x;
    const float Vo1 = pb0*q0.y + pb1*q1.y + pb2*q2.y;
    const float Vo2 = pb0*q0.z + pb1*q1.z + pb2*q2.z;
    const float Vo3 = pb0*q0.w + pb1*q1.w + pb2*q2.w;

    float VeM = __shfl_up(Ve3, 1);     // left neighbor's Ve[3]
    float VoM = __shfl_up(Vo3, 1);
    float VeP = __shfl_down(Ve0, 1);   // right neighbor's Ve[0]
    float VoP = __shfl_down(Vo0, 1);
    if (needL) { VeM = pa0*s0 + pa1*s1; VoM = pb0*s0 + pb1*s1 + pb2*s2; }
    if (needR) { VeP = pa0*s0 + pa1*s1; VoP = pb0*s0 + pb1*s1 + pb2*s2; }

    // horizontal taps (v0 = 1): even col 2-tap, odd col 3-tap
    const float h0i = 0.75f + 0.25f*vv1;
    const float h1i = 0.25f + 0.75f*vv1;
    const float g0i = 0.25f;
    const float g1i = 0.75f*(1.f + vv1);
    const float g2i = 0.25f*vv1;
    const float h0a = le ? 0.f : h0i;                 // pair0 @ image left edge
    const float h1a = le ? vv1 : h1i;
    const float g0a = le ? 0.f : g0i;
    const float g1a = le ? (1.f + 0.75f*vv1) : g1i;
    const float g1d = re ? (0.75f + vv1) : g1i;       // pair3 @ image right edge
    const float g2d = re ? 0.f : g2i;

    // pair 0 (x = x0)
    e0 += h0a*VeM + h1a*Ve0;
    e1 += g0a*VeM + g1a*Ve0 + g2i*Ve1;
    o0 += h0a*VoM + h1a*Vo0;
    o1 += g0a*VoM + g1a*Vo0 + g2i*Vo1;
    // pair 1
    e2 += h0i*Ve0 + h1i*Ve1;
    e3 += g0i*Ve0 + g1i*Ve1 + g2i*Ve2;
    o2 += h0i*Vo0 + h1i*Vo1;
    o3 += g0i*Vo0 + g1i*Vo1 + g2i*Vo2;
    // pair 2
    e4 += h0i*Ve1 + h1i*Ve2;
    e5 += g0i*Ve1 + g1i*Ve2 + g2i*Ve3;
    o4 += h0i*Vo1 + h1i*Vo2;
    o5 += g0i*Vo1 + g1i*Vo2 + g2i*Vo3;
    // pair 3
    e6 += h0i*Ve2 + h1i*Ve3;
    e7 += g0i*Ve2 + g1d*Ve3 + g2d*VeP;
    o6 += h0i*Vo2 + h1i*Vo3;
    o7 += g0i*Vo2 + g1d*Vo3 + g2d*VoP;
  }

  float* op = out + ((size_t)bc * OH + 2 * y) * OW + 2 * x0;
  const f32x4 E0 = { e0, e1, e2, e3 };
  const f32x4 E1 = { e4, e5, e6, e7 };
  const f32x4 O0 = { o0, o1, o2, o3 };
  const f32x4 O1 = { o4, o5, o6, o7 };
  __builtin_nontemporal_store(E0, (f32x4*)op);
  __builtin_nontemporal_store(E1, (f32x4*)(op + 4));
  __builtin_nontemporal_store(O0, (f32x4*)(op + OW));
  __builtin_nontemporal_store(O1, (f32x4*)(op + OW + 4));
}

} // namespace

extern "C" void kernel_launch(void* const* d_in, const int* in_sizes, int n_in,
                              void* d_out, int out_size, void* d_ws, size_t ws_size,
                              hipStream_t stream) {
  const float* x   = (const float*)d_in[0];
  const float* fll = (const float*)d_in[1];
  const float* flh = (const float*)d_in[2];
  const float* fhl = (const float*)d_in[3];
  const float* fhh = (const float*)d_in[4];
  float* out = (float*)d_out;

  ihaar<<<dim3(NWG), 256, 0, stream>>>(x, fll, flh, fhl, fhh, out);
}

// Round 5
// 68.106 us; speedup vs baseline: 2.3431x; 1.1341x over previous
//
#include <hip/hip_runtime.h>

namespace {

constexpr int Hh = 512, Ww = 512, OH = 1024, OW = 1024;
constexpr int NB_Y = 256;             // y-blocks (2 input rows each)
constexpr int NBC  = 48;              // 16 batches * 3 out channels
constexpr int NWG  = NB_Y * NBC;      // 12288, % 8 == 0

typedef float f32x4 __attribute__((ext_vector_type(4)));

// Haar butterfly structure: bands {0,1} share horizontal ratio vP=f01/f00,
// bands {2,3} share vQ. out = H_vP(V_u0(b0)+V_u1(b1)) + H_vQ(V_u2(b2)+V_u3(b3)).
// Thread: 1 input row, 4 cols -> 8x2 output strip. Wave = 256-col half-row;
// neighbors via shfl; 2 seam lanes/wave do predicated scalar loads.
__global__ __launch_bounds__(256) void ihaar(
    const float* __restrict__ x,
    const float* __restrict__ f0,
    const float* __restrict__ f1,
    const float* __restrict__ f2,
    const float* __restrict__ f3,
    float* __restrict__ out)
{
  // XCD-chunked bijective swizzle (NWG % 8 == 0)
  const int bid = blockIdx.x;
  const int wg  = (bid & 7) * (NWG / 8) + (bid >> 3);
  const int bc   = wg / NB_Y;
  const int yblk = wg - bc * NB_Y;
  const int b = bc / 3;
  const int c = bc - 3 * b;

  const int t    = threadIdx.x;
  const int lane = t & 63;
  const int wv   = t >> 6;
  const int half = wv & 1;
  const int ty   = wv >> 1;
  const int y    = 2 * yblk + ty;
  const int x0   = half * 256 + lane * 4;

  const float4 F[4] = { *(const float4*)f0, *(const float4*)f1,
                        *(const float4*)f2, *(const float4*)f3 };

  const int u0r = (y > 0) ? y - 1 : 0;
  const int u2r = (y < Hh - 1) ? y + 1 : y;
  const bool needL = (lane == 0)  && (half == 1);   // needs col 255
  const bool needR = (lane == 63) && (half == 0);   // needs col 256
  const bool le = (x0 == 0), re = (x0 == Ww - 4);
  const int sc = needL ? (x0 - 1) : (x0 + 4);

  // group accumulators: vertical-combined values at 4 cols, even/odd up-row
  float Pe0=0.f,Pe1=0.f,Pe2=0.f,Pe3=0.f, Po0=0.f,Po1=0.f,Po2=0.f,Po3=0.f;
  float Qe0=0.f,Qe1=0.f,Qe2=0.f,Qe3=0.f, Qo0=0.f,Qo1=0.f,Qo2=0.f,Qo3=0.f;
  float SPe=0.f,SPo=0.f,SQe=0.f,SQo=0.f;  // seam-col vertical values

#define BAND(g, Ae0,Ae1,Ae2,Ae3, Ao0,Ao1,Ao2,Ao3, Se, So) { \
    const float uu0 = F[g].x, uu1 = F[g].z; \
    float pa0, pa1, pb0, pb1, pb2; \
    if (y > 0) { pa0 = 0.75f*uu0 + 0.25f*uu1; pa1 = 0.25f*uu0 + 0.75f*uu1; } \
    else       { pa0 = 0.f;                   pa1 = uu1; } \
    if (y == 0)           { pb0 = 0.f;         pb1 = uu0 + 0.75f*uu1; pb2 = 0.25f*uu1; } \
    else if (y == Hh - 1) { pb0 = 0.25f*uu0;   pb1 = 0.75f*uu0 + uu1; pb2 = 0.f; } \
    else                  { pb0 = 0.25f*uu0;   pb1 = 0.75f*(uu0+uu1); pb2 = 0.25f*uu1; } \
    const float* Xp = x + (size_t)(b * 12 + (g) * 3 + c) * (Hh * Ww); \
    const f32x4 q0 = *(const f32x4*)(Xp + (size_t)u0r * Ww + x0); \
    const f32x4 q1 = *(const f32x4*)(Xp + (size_t)y   * Ww + x0); \
    const f32x4 q2 = *(const f32x4*)(Xp + (size_t)u2r * Ww + x0); \
    Ae0 += pa0*q0.x + pa1*q1.x;  Ae1 += pa0*q0.y + pa1*q1.y; \
    Ae2 += pa0*q0.z + pa1*q1.z;  Ae3 += pa0*q0.w + pa1*q1.w; \
    Ao0 += pb0*q0.x + pb1*q1.x + pb2*q2.x; \
    Ao1 += pb0*q0.y + pb1*q1.y + pb2*q2.y; \
    Ao2 += pb0*q0.z + pb1*q1.z + pb2*q2.z; \
    Ao3 += pb0*q0.w + pb1*q1.w + pb2*q2.w; \
    if (needL || needR) { \
      const float s0 = Xp[(size_t)u0r * Ww + sc]; \
      const float s1 = Xp[(size_t)y   * Ww + sc]; \
      const float s2 = Xp[(size_t)u2r * Ww + sc]; \
      Se += pa0*s0 + pa1*s1;  So += pb0*s0 + pb1*s1 + pb2*s2; \
    } \
  }

  BAND(0, Pe0,Pe1,Pe2,Pe3, Po0,Po1,Po2,Po3, SPe, SPo)
  BAND(1, Pe0,Pe1,Pe2,Pe3, Po0,Po1,Po2,Po3, SPe, SPo)
  BAND(2, Qe0,Qe1,Qe2,Qe3, Qo0,Qo1,Qo2,Qo3, SQe, SQo)
  BAND(3, Qe0,Qe1,Qe2,Qe3, Qo0,Qo1,Qo2,Qo3, SQe, SQo)
#undef BAND

  // neighbor vertical values across lanes (seam lanes patch from scalar loads)
  float PeL = __shfl_up(Pe3, 1),  PoL = __shfl_up(Po3, 1);
  float QeL = __shfl_up(Qe3, 1),  QoL = __shfl_up(Qo3, 1);
  float PeR = __shfl_down(Pe0, 1), PoR = __shfl_down(Po0, 1);
  float QeR = __shfl_down(Qe0, 1), QoR = __shfl_down(Qo0, 1);
  if (needL) { PeL = SPe; PoL = SPo; QeL = SQe; QoL = SQo; }
  if (needR) { PeR = SPe; PoR = SPo; QeR = SQe; QoR = SQo; }

  // horizontal taps per group (v0 = 1, ratio v1 = f01/f00; rcp exact: f00=0.5)
  const float vp = F[0].y * __builtin_amdgcn_rcpf(F[0].x);
  const float vq = F[2].y * __builtin_amdgcn_rcpf(F[2].x);
  const float h0p = 0.75f + 0.25f*vp, h1p = 0.25f + 0.75f*vp;
  const float g0p = 0.25f, g1p = 0.75f*(1.f + vp), g2p = 0.25f*vp;
  const float h0q = 0.75f + 0.25f*vq, h1q = 0.25f + 0.75f*vq;
  const float g0q = 0.25f, g1q = 0.75f*(1.f + vq), g2q = 0.25f*vq;
  // image-edge variants
  const float h0pa = le ? 0.f : h0p, h1pa = le ? vp : h1p;
  const float g0pa = le ? 0.f : g0p, g1pa = le ? (1.f + 0.75f*vp) : g1p;
  const float g1pd = re ? (0.75f + vp) : g1p, g2pd = re ? 0.f : g2p;
  const float h0qa = le ? 0.f : h0q, h1qa = le ? vq : h1q;
  const float g0qa = le ? 0.f : g0q, g1qa = le ? (1.f + 0.75f*vq) : g1q;
  const float g1qd = re ? (0.75f + vq) : g1q, g2qd = re ? 0.f : g2q;

  // even-parity output row (2y)
  const float e0 = h0pa*PeL + h1pa*Pe0           + h0qa*QeL + h1qa*Qe0;
  const float e1 = g0pa*PeL + g1pa*Pe0 + g2p*Pe1 + g0qa*QeL + g1qa*Qe0 + g2q*Qe1;
  const float e2 = h0p*Pe0  + h1p*Pe1            + h0q*Qe0  + h1q*Qe1;
  const float e3 = g0p*Pe0  + g1p*Pe1  + g2p*Pe2 + g0q*Qe0  + g1q*Qe1  + g2q*Qe2;
  const float e4 = h0p*Pe1  + h1p*Pe2            + h0q*Qe1  + h1q*Qe2;
  const float e5 = g0p*Pe1  + g1p*Pe2  + g2p*Pe3 + g0q*Qe1  + g1q*Qe2  + g2q*Qe3;
  const float e6 = h0p*Pe2  + h1p*Pe3            + h0q*Qe2  + h1q*Qe3;
  const float e7 = g0p*Pe2  + g1pd*Pe3 + g2pd*PeR+ g0q*Qe2  + g1qd*Qe3 + g2qd*QeR;
  // odd-parity output row (2y+1)
  const float o0 = h0pa*PoL + h1pa*Po0           + h0qa*QoL + h1qa*Qo0;
  const float o1 = g0pa*PoL + g1pa*Po0 + g2p*Po1 + g0qa*QoL + g1qa*Qo0 + g2q*Qo1;
  const float o2 = h0p*Po0  + h1p*Po1            + h0q*Qo0  + h1q*Qo1;
  const float o3 = g0p*Po0  + g1p*Po1  + g2p*Po2 + g0q*Qo0  + g1q*Qo1  + g2q*Qo2;
  const float o4 = h0p*Po1  + h1p*Po2            + h0q*Qo1  + h1q*Qo2;
  const float o5 = g0p*Po1  + g1p*Po2  + g2p*Po3 + g0q*Qo1  + g1q*Qo2  + g2q*Qo3;
  const float o6 = h0p*Po2  + h1p*Po3            + h0q*Qo2  + h1q*Qo3;
  const float o7 = g0p*Po2  + g1pd*Po3 + g2pd*PoR+ g0q*Qo2  + g1qd*Qo3 + g2qd*QoR;

  float* op = out + ((size_t)bc * OH + 2 * y) * OW + 2 * x0;
  const f32x4 E0 = { e0, e1, e2, e3 };
  const f32x4 E1 = { e4, e5, e6, e7 };
  const f32x4 O0 = { o0, o1, o2, o3 };
  const f32x4 O1 = { o4, o5, o6, o7 };
  __builtin_nontemporal_store(E0, (f32x4*)op);
  __builtin_nontemporal_store(E1, (f32x4*)(op + 4));
  __builtin_nontemporal_store(O0, (f32x4*)(op + OW));
  __builtin_nontemporal_store(O1, (f32x4*)(op + OW + 4));
}

} // namespace

extern "C" void kernel_launch(void* const* d_in, const int* in_sizes, int n_in,
                              void* d_out, int out_size, void* d_ws, size_t ws_size,
                              hipStream_t stream) {
  const float* x   = (const float*)d_in[0];
  const float* fll = (const float*)d_in[1];
  const float* flh = (const float*)d_in[2];
  const float* fhl = (const float*)d_in[3];
  const float* fhh = (const float*)d_in[4];
  float* out = (float*)d_out;

  ihaar<<<dim3(NWG), 256, 0, stream>>>(x, fll, flh, fhl, fhh, out);
}

// Round 6
// 64.608 us; speedup vs baseline: 2.4699x; 1.0541x over previous
//
#include <hip/hip_runtime.h>

namespace {

constexpr int Hh = 512, Ww = 512, OH = 1024, OW = 1024;
constexpr int NB_Y = 256;             // y-blocks (2 input rows each)
constexpr int NBC  = 48;              // 16 batches * 3 out channels
constexpr int NWG  = NB_Y * NBC;      // 12288, % 8 == 0

typedef float f32x4 __attribute__((ext_vector_type(4)));

// Haar butterfly: bands {0,1} share horizontal ratio vP, {2,3} share vQ.
// out = H_vP(V_u0(b0)+V_u1(b1)) + H_vQ(V_u2(b2)+V_u3(b3)).
// All 12 float4 loads issued up-front for MLP; math after.
__global__ __launch_bounds__(256) void ihaar(
    const float* __restrict__ x,
    const float* __restrict__ f0,
    const float* __restrict__ f1,
    const float* __restrict__ f2,
    const float* __restrict__ f3,
    float* __restrict__ out)
{
  // XCD-chunked bijective swizzle (NWG % 8 == 0)
  const int bid = blockIdx.x;
  const int wg  = (bid & 7) * (NWG / 8) + (bid >> 3);
  const int bc   = wg / NB_Y;
  const int yblk = wg - bc * NB_Y;
  const int b = bc / 3;
  const int c = bc - 3 * b;

  const int t    = threadIdx.x;
  const int lane = t & 63;
  const int wv   = t >> 6;
  const int half = wv & 1;
  const int ty   = wv >> 1;
  const int y    = 2 * yblk + ty;
  const int x0   = half * 256 + lane * 4;

  const int u0r = (y > 0) ? y - 1 : 0;
  const int u2r = (y < Hh - 1) ? y + 1 : y;
  const bool needL = (lane == 0)  && (half == 1);   // needs col 255
  const bool needR = (lane == 63) && (half == 0);   // needs col 256
  const bool seam  = needL || needR;
  const bool le = (x0 == 0), re = (x0 == Ww - 4);
  const int sc = needL ? (x0 - 1) : (x0 + 4);

  const size_t HW = (size_t)Hh * Ww;
  const float* Xa = x + (size_t)(b * 12 + c) * HW;   // band g at Xa + g*3*HW
  const float* Xb = Xa + 3 * HW;
  const float* Xc = Xa + 6 * HW;
  const float* Xd = Xa + 9 * HW;
  const size_t r0 = (size_t)u0r * Ww + x0;
  const size_t r1 = (size_t)y   * Ww + x0;
  const size_t r2 = (size_t)u2r * Ww + x0;

  // ---- issue ALL loads first (12 x dwordx4 + predicated seam scalars) ----
  const f32x4 qA0 = *(const f32x4*)(Xa + r0);
  const f32x4 qA1 = *(const f32x4*)(Xa + r1);
  const f32x4 qA2 = *(const f32x4*)(Xa + r2);
  const f32x4 qB0 = *(const f32x4*)(Xb + r0);
  const f32x4 qB1 = *(const f32x4*)(Xb + r1);
  const f32x4 qB2 = *(const f32x4*)(Xb + r2);
  const f32x4 qC0 = *(const f32x4*)(Xc + r0);
  const f32x4 qC1 = *(const f32x4*)(Xc + r1);
  const f32x4 qC2 = *(const f32x4*)(Xc + r2);
  const f32x4 qD0 = *(const f32x4*)(Xd + r0);
  const f32x4 qD1 = *(const f32x4*)(Xd + r1);
  const f32x4 qD2 = *(const f32x4*)(Xd + r2);

  float sA0=0.f,sA1=0.f,sA2=0.f, sB0=0.f,sB1=0.f,sB2=0.f;
  float sC0=0.f,sC1=0.f,sC2=0.f, sD0=0.f,sD1=0.f,sD2=0.f;
  if (seam) {
    const size_t t0 = (size_t)u0r * Ww + sc;
    const size_t t1 = (size_t)y   * Ww + sc;
    const size_t t2 = (size_t)u2r * Ww + sc;
    sA0 = Xa[t0]; sA1 = Xa[t1]; sA2 = Xa[t2];
    sB0 = Xb[t0]; sB1 = Xb[t1]; sB2 = Xb[t2];
    sC0 = Xc[t0]; sC1 = Xc[t1]; sC2 = Xc[t2];
    sD0 = Xd[t0]; sD1 = Xd[t1]; sD2 = Xd[t2];
  }

  const float4 F[4] = { *(const float4*)f0, *(const float4*)f1,
                        *(const float4*)f2, *(const float4*)f3 };

  // group accumulators: vertical-combined values at 4 cols, even/odd up-row
  float Pe0,Pe1,Pe2,Pe3, Po0,Po1,Po2,Po3;
  float Qe0,Qe1,Qe2,Qe3, Qo0,Qo1,Qo2,Qo3;
  float SPe=0.f,SPo=0.f,SQe=0.f,SQo=0.f;

#define VTAPS(g, pa0,pa1,pb0,pb1,pb2) \
    float pa0, pa1, pb0, pb1, pb2; { \
    const float uu0 = F[g].x, uu1 = F[g].z; \
    if (y > 0) { pa0 = 0.75f*uu0 + 0.25f*uu1; pa1 = 0.25f*uu0 + 0.75f*uu1; } \
    else       { pa0 = 0.f;                   pa1 = uu1; } \
    if (y == 0)           { pb0 = 0.f;       pb1 = uu0 + 0.75f*uu1; pb2 = 0.25f*uu1; } \
    else if (y == Hh - 1) { pb0 = 0.25f*uu0; pb1 = 0.75f*uu0 + uu1; pb2 = 0.f; } \
    else                  { pb0 = 0.25f*uu0; pb1 = 0.75f*(uu0+uu1); pb2 = 0.25f*uu1; } }

  VTAPS(0, aA0,aA1,bA0,bA1,bA2)
  VTAPS(1, aB0,aB1,bB0,bB1,bB2)
  VTAPS(2, aC0,aC1,bC0,bC1,bC2)
  VTAPS(3, aD0,aD1,bD0,bD1,bD2)
#undef VTAPS

  Pe0 = aA0*qA0.x + aA1*qA1.x + aB0*qB0.x + aB1*qB1.x;
  Pe1 = aA0*qA0.y + aA1*qA1.y + aB0*qB0.y + aB1*qB1.y;
  Pe2 = aA0*qA0.z + aA1*qA1.z + aB0*qB0.z + aB1*qB1.z;
  Pe3 = aA0*qA0.w + aA1*qA1.w + aB0*qB0.w + aB1*qB1.w;
  Po0 = bA0*qA0.x + bA1*qA1.x + bA2*qA2.x + bB0*qB0.x + bB1*qB1.x + bB2*qB2.x;
  Po1 = bA0*qA0.y + bA1*qA1.y + bA2*qA2.y + bB0*qB0.y + bB1*qB1.y + bB2*qB2.y;
  Po2 = bA0*qA0.z + bA1*qA1.z + bA2*qA2.z + bB0*qB0.z + bB1*qB1.z + bB2*qB2.z;
  Po3 = bA0*qA0.w + bA1*qA1.w + bA2*qA2.w + bB0*qB0.w + bB1*qB1.w + bB2*qB2.w;
  Qe0 = aC0*qC0.x + aC1*qC1.x + aD0*qD0.x + aD1*qD1.x;
  Qe1 = aC0*qC0.y + aC1*qC1.y + aD0*qD0.y + aD1*qD1.y;
  Qe2 = aC0*qC0.z + aC1*qC1.z + aD0*qD0.z + aD1*qD1.z;
  Qe3 = aC0*qC0.w + aC1*qC1.w + aD0*qD0.w + aD1*qD1.w;
  Qo0 = bC0*qC0.x + bC1*qC1.x + bC2*qC2.x + bD0*qD0.x + bD1*qD1.x + bD2*qD2.x;
  Qo1 = bC0*qC0.y + bC1*qC1.y + bC2*qC2.y + bD0*qD0.y + bD1*qD1.y + bD2*qD2.y;
  Qo2 = bC0*qC0.z + bC1*qC1.z + bC2*qC2.z + bD0*qD0.z + bD1*qD1.z + bD2*qD2.z;
  Qo3 = bC0*qC0.w + bC1*qC1.w + bC2*qC2.w + bD0*qD0.w + bD1*qD1.w + bD2*qD2.w;
  if (seam) {
    SPe = aA0*sA0 + aA1*sA1 + aB0*sB0 + aB1*sB1;
    SPo = bA0*sA0 + bA1*sA1 + bA2*sA2 + bB0*sB0 + bB1*sB1 + bB2*sB2;
    SQe = aC0*sC0 + aC1*sC1 + aD0*sD0 + aD1*sD1;
    SQo = bC0*sC0 + bC1*sC1 + bC2*sC2 + bD0*sD0 + bD1*sD1 + bD2*sD2;
  }

  // neighbor vertical values across lanes (seam lanes patch from scalars)
  float PeL = __shfl_up(Pe3, 1),  PoL = __shfl_up(Po3, 1);
  float QeL = __shfl_up(Qe3, 1),  QoL = __shfl_up(Qo3, 1);
  float PeR = __shfl_down(Pe0, 1), PoR = __shfl_down(Po0, 1);
  float QeR = __shfl_down(Qe0, 1), QoR = __shfl_down(Qo0, 1);
  if (needL) { PeL = SPe; PoL = SPo; QeL = SQe; QoL = SQo; }
  if (needR) { PeR = SPe; PoR = SPo; QeR = SQe; QoR = SQo; }

  // horizontal taps per group (v0 = 1, ratio v1 = f01/f00; rcp exact: f00=±0.5)
  const float vp = F[0].y * __builtin_amdgcn_rcpf(F[0].x);
  const float vq = F[2].y * __builtin_amdgcn_rcpf(F[2].x);
  const float h0p = 0.75f + 0.25f*vp, h1p = 0.25f + 0.75f*vp;
  const float g0p = 0.25f, g1p = 0.75f*(1.f + vp), g2p = 0.25f*vp;
  const float h0q = 0.75f + 0.25f*vq, h1q = 0.25f + 0.75f*vq;
  const float g0q = 0.25f, g1q = 0.75f*(1.f + vq), g2q = 0.25f*vq;
  const float h0pa = le ? 0.f : h0p, h1pa = le ? vp : h1p;
  const float g0pa = le ? 0.f : g0p, g1pa = le ? (1.f + 0.75f*vp) : g1p;
  const float g1pd = re ? (0.75f + vp) : g1p, g2pd = re ? 0.f : g2p;
  const float h0qa = le ? 0.f : h0q, h1qa = le ? vq : h1q;
  const float g0qa = le ? 0.f : g0q, g1qa = le ? (1.f + 0.75f*vq) : g1q;
  const float g1qd = re ? (0.75f + vq) : g1q, g2qd = re ? 0.f : g2q;

  // even-parity output row (2y)
  const float e0 = h0pa*PeL + h1pa*Pe0           + h0qa*QeL + h1qa*Qe0;
  const float e1 = g0pa*PeL + g1pa*Pe0 + g2p*Pe1 + g0qa*QeL + g1qa*Qe0 + g2q*Qe1;
  const float e2 = h0p*Pe0  + h1p*Pe1            + h0q*Qe0  + h1q*Qe1;
  const float e3 = g0p*Pe0  + g1p*Pe1  + g2p*Pe2 + g0q*Qe0  + g1q*Qe1  + g2q*Qe2;
  const float e4 = h0p*Pe1  + h1p*Pe2            + h0q*Qe1  + h1q*Qe2;
  const float e5 = g0p*Pe1  + g1p*Pe2  + g2p*Pe3 + g0q*Qe1  + g1q*Qe2  + g2q*Qe3;
  const float e6 = h0p*Pe2  + h1p*Pe3            + h0q*Qe2  + h1q*Qe3;
  const float e7 = g0p*Pe2  + g1pd*Pe3 + g2pd*PeR+ g0q*Qe2  + g1qd*Qe3 + g2qd*QeR;
  // odd-parity output row (2y+1)
  const float o0 = h0pa*PoL + h1pa*Po0           + h0qa*QoL + h1qa*Qo0;
  const float o1 = g0pa*PoL + g1pa*Po0 + g2p*Po1 + g0qa*QoL + g1qa*Qo0 + g2q*Qo1;
  const float o2 = h0p*Po0  + h1p*Po1            + h0q*Qo0  + h1q*Qo1;
  const float o3 = g0p*Po0  + g1p*Po1  + g2p*Po2 + g0q*Qo0  + g1q*Qo1  + g2q*Qo2;
  const float o4 = h0p*Po1  + h1p*Po2            + h0q*Qo1  + h1q*Qo2;
  const float o5 = g0p*Po1  + g1p*Po2  + g2p*Po3 + g0q*Qo1  + g1q*Qo2  + g2q*Qo3;
  const float o6 = h0p*Po2  + h1p*Po3            + h0q*Qo2  + h1q*Qo3;
  const float o7 = g0p*Po2  + g1pd*Po3 + g2pd*PoR+ g0q*Qo2  + g1qd*Qo3 + g2qd*QoR;

  float* op = out + ((size_t)bc * OH + 2 * y) * OW + 2 * x0;
  const f32x4 E0 = { e0, e1, e2, e3 };
  const f32x4 E1 = { e4, e5, e6, e7 };
  const f32x4 O0 = { o0, o1, o2, o3 };
  const f32x4 O1 = { o4, o5, o6, o7 };
  __builtin_nontemporal_store(E0, (f32x4*)op);
  __builtin_nontemporal_store(E1, (f32x4*)(op + 4));
  __builtin_nontemporal_store(O0, (f32x4*)(op + OW));
  __builtin_nontemporal_store(O1, (f32x4*)(op + OW + 4));
}

} // namespace

extern "C" void kernel_launch(void* const* d_in, const int* in_sizes, int n_in,
                              void* d_out, int out_size, void* d_ws, size_t ws_size,
                              hipStream_t stream) {
  const float* x   = (const float*)d_in[0];
  const float* fll = (const float*)d_in[1];
  const float* flh = (const float*)d_in[2];
  const float* fhl = (const float*)d_in[3];
  const float* fhh = (const float*)d_in[4];
  float* out = (float*)d_out;

  ihaar<<<dim3(NWG), 256, 0, stream>>>(x, fll, flh, fhl, fhh, out);
}